// Round 4
// baseline (1158.892 us; speedup 1.0000x reference)
//
// MOE anomaly detection — MI355X round 4.
// Fix vs r3: ws offset table sized W2F as 131072 (element count) instead of
// 262144 BYTES -> k_wprep W2f writes for e>=8 clobbered Wgf/vfold/xbar/bn2
// stats/mean1/istd1 (NaN via rsqrtf(negative) and garbage vfold floats).
// All offsets after W2F shifted +131072. No kernel-body changes.
#include <hip/hip_runtime.h>
#include <stdint.h>

#define NTOK 65536
#define DDIM 512
#define NE   16
#define NH1  128
#define NH2  64
#define NR   32

typedef __attribute__((ext_vector_type(8))) short short8;
typedef __attribute__((ext_vector_type(4))) unsigned short ushort4_t;
typedef __attribute__((ext_vector_type(4))) float f32x4;

__device__ __forceinline__ unsigned short f2bf(float f) {
  union { float f; uint32_t u; } v; v.f = f;
  uint32_t u = v.u;
  return (unsigned short)((u + 0x7FFFu + ((u >> 16) & 1u)) >> 16);
}
__device__ __forceinline__ float bf2f(unsigned short h) {
  union { uint32_t u; float f; } v; v.u = ((uint32_t)h) << 16;
  return v.f;
}

// ---------------- ws layout (bytes) ----------------
// lifetimes: xTf: k_prep->k_cov. covp: k_cov->k_covred. Both dead before k_main
// writes h2p, so h2p aliases them.
#define OFF_XF     ((size_t)0)            // bf16 xf   frag-tiled             67108864
#define OFF_H2     ((size_t)67108864)     // bf16 h2_pre [N][16][64]         134217728
#define OFF_XTF    ((size_t)67108864)     // bf16 xTf  frag-tiled (ALIAS h2)  67108864
#define OFF_COVP   ((size_t)134217728)    // f32 covp [1280][128][128] (ALIAS)83886080
#define OFF_C      ((size_t)218103808)    // f32 C [512][512]                  1048576
#define OFF_GATE   ((size_t)219152384)    // f32 gate [N][16]                  4194304
#define OFF_W1F    ((size_t)223346688)    // bf16 W1f frag-tiled               2097152
#define OFF_W1T    ((size_t)225443840)    // bf16 W1t row-major (k_bn1)        2097152
#define OFF_W2F    ((size_t)227540992)    // bf16 W2f frag-tiled [16][8192]sh   262144
#define OFF_WGF    ((size_t)227803136)    // bf16 Wgf frag-tiled                 16384
#define OFF_V      ((size_t)227819520)    // f32 v=W3@Ws [16][64]                 4096
#define OFF_XBAR   ((size_t)227823616)    // f32 xbar[512]   (zero region)        2048
#define OFF_BN2S   ((size_t)227825664)    // f32 bn2 sum[1024]                    4096
#define OFF_BN2SS  ((size_t)227829760)    // f32 bn2 sumsq[1024]                  4096
#define OFF_MEAN1  ((size_t)227833856)    // f32 mean1[16][128]                   8192
#define OFF_ISTD1  ((size_t)227842048)    // f32 istd1[16][128]                   8192
// total 227850240 B (~217 MB); r2 proved >=242MB available.

// Fragment-tiled index helpers (16-row tiles, 8-elem k-groups):
//  frag_idx(tileIdx, G, i, j) = tileIdx*(<Kgroups>*128) + G*128 + i*8 + j
//  A wave's 16x32-k fragment load: lanes (i=lr, G=G0+lg) -> contiguous 1KB.

// ============ k_wprep: weight convert to frag layouts + fold + zero ============
__global__ __launch_bounds__(256) void k_wprep(
    const float* __restrict__ W1, const float* __restrict__ W2,
    const float* __restrict__ W3, const float* __restrict__ Wg,
    const float* __restrict__ Ws,
    unsigned short* __restrict__ W1f, unsigned short* __restrict__ W1t,
    unsigned short* __restrict__ W2f, unsigned short* __restrict__ Wgf,
    float* __restrict__ vfold, float* __restrict__ zeroreg)
{
  int b = blockIdx.x, t = threadIdx.x;
  if (b < 512) {            // W1 [E][D][H1] -> W1f frag: e,h-tile,G=d>>3,h&15,d&7
    int f = b * 256 + t;                 // 131072 chunks
    int d8 = f & 63, h = (f >> 6) & 127, e = f >> 13;
    short8 s;
#pragma unroll
    for (int i = 0; i < 8; ++i)
      s[i] = (short)f2bf(W1[((e * DDIM + d8 * 8 + i) * NH1) + h]);
    *(short8*)&W1f[e * 65536 + (h >> 4) * 8192 + d8 * 128 + (h & 15) * 8] = s;
  } else if (b < 1024) {    // W1 -> W1t [E][H1][D] row-major (for k_bn1)
    int f = (b - 512) * 256 + t;
    int h = f & 127, d8 = (f >> 7) & 63, e = f >> 13;
    short8 s;
#pragma unroll
    for (int i = 0; i < 8; ++i)
      s[i] = (short)f2bf(W1[((e * DDIM + d8 * 8 + i) * NH1) + h]);
    *(short8*)&W1t[(e * NH1 + h) * DDIM + d8 * 8] = s;
  } else if (b < 1088) {    // W2 [E][H1][H2] -> W2f frag: e,h2-tile,G=h1>>3,h2&15,h1&7
    int f = (b - 1024) * 256 + t;        // 16384 chunks
    int h18 = f & 15, h2 = (f >> 4) & 63, e = f >> 10;
    short8 s;
#pragma unroll
    for (int i = 0; i < 8; ++i)
      s[i] = (short)f2bf(W2[((e * NH1 + h18 * 8 + i) * NH2) + h2]);
    *(short8*)&W2f[e * 8192 + (h2 >> 4) * 2048 + h18 * 128 + (h2 & 15) * 8] = s;
  } else if (b < 1092) {    // Wg [D][E] -> Wgf frag (single 16-col tile)
    int f = (b - 1088) * 256 + t;        // 1024 chunks
    int e = f & 15, dg = f >> 4;
    short8 s;
#pragma unroll
    for (int i = 0; i < 8; ++i)
      s[i] = (short)f2bf(Wg[(dg * 8 + i) * NE + e]);
    *(short8*)&Wgf[dg * 128 + e * 8] = s;
  } else if (b < 1096) {    // vfold[e][h] = sum_r W3[e][h][r]*Ws[r]
    int f = (b - 1092) * 256 + t;
    if (f < NE * NH2) {
      int h = f & 63, e = f >> 6;
      float a = 0.f;
#pragma unroll
      for (int r = 0; r < NR; ++r) a += W3[(e * NH2 + h) * NR + r] * Ws[r];
      vfold[e * NH2 + h] = a;
    }
  } else {                  // zero xbar(512)+bn2s(1024)+bn2ss(1024)
    int f = (b - 1096) * 256 + t;
    if (f < 2560) zeroreg[f] = 0.f;
  }
}

// ============ k_prep: x fp32 -> xf (token-frag) + xTf (d-frag) + column sums ====
__global__ __launch_bounds__(256) void k_prep(const float* __restrict__ x,
                                              unsigned short* __restrict__ xf,
                                              unsigned short* __restrict__ xTf,
                                              float* __restrict__ xbar)
{
  __shared__ unsigned short tl[64 * 72];   // [d][n] transposed tile, pad 72
  __shared__ float red[16 * 64];
  int b = blockIdx.x, t = threadIdx.x;
  int dt = b >> 10, nt = b & 1023;
  int d0 = dt * 64, n0 = nt * 64;
  int rg = t >> 4, c4 = (t & 15) * 4;
  float s0 = 0, s1 = 0, s2 = 0, s3 = 0;
#pragma unroll
  for (int i = 0; i < 4; ++i) {
    int r = i * 16 + rg;
    float4 v = *(const float4*)&x[(size_t)(n0 + r) * DDIM + d0 + c4];
    s0 += v.x; s1 += v.y; s2 += v.z; s3 += v.w;
    ushort4_t u;
    u.x = f2bf(v.x); u.y = f2bf(v.y); u.z = f2bf(v.z); u.w = f2bf(v.w);
    tl[(c4 + 0) * 72 + r] = u.x;
    tl[(c4 + 1) * 72 + r] = u.y;
    tl[(c4 + 2) * 72 + r] = u.z;
    tl[(c4 + 3) * 72 + r] = u.w;
    int n = n0 + r, dd = d0 + c4;
    *(ushort4_t*)&xf[(size_t)(n >> 4) * 8192 + (dd >> 3) * 128 + (n & 15) * 8 + (dd & 7)] = u;
  }
  red[rg * 64 + c4 + 0] = s0;
  red[rg * 64 + c4 + 1] = s1;
  red[rg * 64 + c4 + 2] = s2;
  red[rg * 64 + c4 + 3] = s3;
  __syncthreads();
  if (t < 64) {
    float s = 0;
#pragma unroll
    for (int k = 0; k < 16; ++k) s += red[k * 64 + t];
    atomicAdd(&xbar[d0 + t], s);
  }
#pragma unroll
  for (int ii = 0; ii < 2; ++ii) {
    int cid = ii * 256 + t;
    int dl = cid >> 3, ng = cid & 7;
    short8 v = *(short8*)&tl[dl * 72 + ng * 8];
    int dg = d0 + dl;
    *(short8*)&xTf[(size_t)(dg >> 4) * 1048576 + (size_t)((n0 >> 3) + ng) * 128 + (dg & 15) * 8] = v;
  }
}

// ============ k_cov: covp partials of C = x^T x, zero LDS, frag-coalesced ======
// grid = 128 K-chunks x 10 upper-triangle 128x128 tiles
__global__ __launch_bounds__(256, 4) void k_cov(const unsigned short* __restrict__ xTf,
                                                float* __restrict__ covp)
{
  int bid = blockIdx.x, t = threadIdx.x;
  int chunk = bid / 10, tile = bid - chunk * 10;
  int ti = tile < 4 ? 0 : tile < 7 ? 1 : tile < 9 ? 2 : 3;
  int tj = tile < 4 ? tile : tile < 7 ? tile - 3 : tile < 9 ? tile - 5 : 3;
  int l = t & 63, wid = t >> 6;            // 4 waves: 2x2 of 64x64
  int lr = l & 15, lg = l >> 4;
  int rt = ti * 8 + (wid >> 1) * 4;        // d-tile base (rows)
  int ct = tj * 8 + (wid & 1) * 4;         // d-tile base (cols)
  int G0 = chunk * 64;                     // n-group base (K=512 per chunk)
  f32x4 acc[4][4];
#pragma unroll
  for (int m = 0; m < 4; ++m)
#pragma unroll
    for (int n = 0; n < 4; ++n) acc[m][n] = (f32x4){0.f, 0.f, 0.f, 0.f};
  for (int ksi = 0; ksi < 16; ++ksi) {
    size_t G = (size_t)(G0 + ksi * 4 + lg);
    short8 av[4], bv[4];
#pragma unroll
    for (int m = 0; m < 4; ++m)
      av[m] = *(const short8*)&xTf[(size_t)(rt + m) * 1048576 + G * 128 + lr * 8];
#pragma unroll
    for (int n = 0; n < 4; ++n)
      bv[n] = *(const short8*)&xTf[(size_t)(ct + n) * 1048576 + G * 128 + lr * 8];
#pragma unroll
    for (int m = 0; m < 4; ++m)
#pragma unroll
      for (int n = 0; n < 4; ++n)
        acc[m][n] = __builtin_amdgcn_mfma_f32_16x16x32_bf16(av[m], bv[n], acc[m][n], 0, 0, 0);
  }
  float* outp = &covp[(size_t)bid * 16384];
#pragma unroll
  for (int m = 0; m < 4; ++m)
#pragma unroll
    for (int n = 0; n < 4; ++n)
#pragma unroll
      for (int r = 0; r < 4; ++r) {
        int rl = (wid >> 1) * 64 + m * 16 + lg * 4 + r;
        int cl = (wid & 1) * 64 + n * 16 + lr;
        outp[rl * 128 + cl] = acc[m][n][r];
      }
}

// ============ k_covred: sum partials, write C (+ mirrored half) ============
__global__ __launch_bounds__(256) void k_covred(const float* __restrict__ covp,
                                                float* __restrict__ C)
{
  int bid = blockIdx.x, t = threadIdx.x;   // 640 blocks
  int tile = bid >> 6;
  int el = (bid & 63) * 256 + t;
  int r = el >> 7, c = el & 127;
  int ti = tile < 4 ? 0 : tile < 7 ? 1 : tile < 9 ? 2 : 3;
  int tj = tile < 4 ? tile : tile < 7 ? tile - 3 : tile < 9 ? tile - 5 : 3;
  float s = 0.f;
#pragma unroll 4
  for (int ch = 0; ch < 128; ++ch)
    s += covp[(size_t)(ch * 10 + tile) * 16384 + r * 128 + c];
  int gi = ti * 128 + r, gj = tj * 128 + c;
  C[gi * 512 + gj] = s;
  if (ti != tj) C[gj * 512 + gi] = s;
}

// ============ k_bn1: mean1 = w.xbar/N ; var1 = w^T C w /N - mean1^2 ============
__global__ __launch_bounds__(256) void k_bn1(const float* __restrict__ C,
                                             const float* __restrict__ xbar,
                                             const unsigned short* __restrict__ W1t,
                                             float* __restrict__ mean1,
                                             float* __restrict__ istd1)
{
  __shared__ float wl[8][512];
  __shared__ float rq[256][8];
  __shared__ float rm[256][8];
  int b = blockIdx.x, t = threadIdx.x;
  int e = b >> 4, ho = (b & 15) * 8;
  for (int f = t; f < 8 * 512; f += 256) {
    int c = f >> 9, d = f & 511;
    wl[c][d] = bf2f(W1t[(e * NH1 + ho + c) * DDIM + d]);
  }
  __syncthreads();
  float q[8] = {0, 0, 0, 0, 0, 0, 0, 0};
  float m[8] = {0, 0, 0, 0, 0, 0, 0, 0};
#pragma unroll
  for (int half = 0; half < 2; ++half) {
    int i = half * 256 + t;
    float rd[8] = {0, 0, 0, 0, 0, 0, 0, 0};
    const float* crow = &C[i * 512];
    for (int j = 0; j < 512; j += 4) {
      float4 cv = *(const float4*)&crow[j];
#pragma unroll
      for (int c = 0; c < 8; ++c)
        rd[c] += cv.x * wl[c][j] + cv.y * wl[c][j + 1] + cv.z * wl[c][j + 2] + cv.w * wl[c][j + 3];
    }
    float xb = xbar[i];
#pragma unroll
    for (int c = 0; c < 8; ++c) { q[c] += wl[c][i] * rd[c]; m[c] += wl[c][i] * xb; }
  }
#pragma unroll
  for (int c = 0; c < 8; ++c) { rq[t][c] = q[c]; rm[t][c] = m[c]; }
  __syncthreads();
  for (int s = 128; s > 0; s >>= 1) {
    if (t < s)
#pragma unroll
      for (int c = 0; c < 8; ++c) { rq[t][c] += rq[t + s][c]; rm[t][c] += rm[t + s][c]; }
    __syncthreads();
  }
  if (t < 8) {
    float mean = rm[0][t] * (1.f / 65536.f);
    float var = rq[0][t] * (1.f / 65536.f) - mean * mean;
    mean1[e * NH1 + ho + t] = mean;
    istd1[e * NH1 + ho + t] = rsqrtf(var + 1e-4f);
  }
}

// ============ k_main: gating + per-expert (GEMM1->BN1->lrelu->GEMM2->h2p) ======
// 512 blocks x 512 thr (8 waves). Swapped-operand MFMA throughout:
// D rows = weight cols, D cols = tokens -> lane holds 4 consecutive weight-cols.
__global__ __launch_bounds__(512, 4) void k_main(
    const unsigned short* __restrict__ xf, const unsigned short* __restrict__ Wgf,
    const unsigned short* __restrict__ W1f, const unsigned short* __restrict__ W2f,
    const float* __restrict__ bg, const float* __restrict__ ln_g,
    const float* __restrict__ ln_b, const float* __restrict__ mean1,
    const float* __restrict__ istd1, float* __restrict__ gate,
    unsigned short* __restrict__ h2p)
{
  __shared__ unsigned short h1l[2][128 * 128];  // 2 x 32KB, XOR-swizzled, dbuf
  int t = threadIdx.x;
  int n0 = blockIdx.x * 128;
  int l = t & 63, wid = t >> 6;
  int lr = l & 15, lg = l >> 4;

  {  // ---- gating: D[e][tok] = Wg^T x^T; LN + softmax over e; float4 store ----
    size_t tokT = (size_t)((n0 >> 4) + wid);
    f32x4 ga = (f32x4){0.f, 0.f, 0.f, 0.f};
    for (int ks = 0; ks < 16; ++ks) {
      int G = ks * 4 + lg;
      short8 avg = *(const short8*)&Wgf[G * 128 + lr * 8];
      short8 bvx = *(const short8*)&xf[tokT * 8192 + G * 128 + lr * 8];
      ga = __builtin_amdgcn_mfma_f32_16x16x32_bf16(avg, bvx, ga, 0, 0, 0);
    }
    // lane: token = wid*16+lr; holds e = lg*4 + r (4 consecutive experts)
    float4 bg4 = *(const float4*)&bg[lg * 4];
    float g0 = ga[0] + bg4.x, g1 = ga[1] + bg4.y, g2 = ga[2] + bg4.z, g3 = ga[3] + bg4.w;
    float s1 = g0 + g1 + g2 + g3;
    float s2 = g0 * g0 + g1 * g1 + g2 * g2 + g3 * g3;
    s1 += __shfl_xor(s1, 16); s1 += __shfl_xor(s1, 32);
    s2 += __shfl_xor(s2, 16); s2 += __shfl_xor(s2, 32);
    float mu = s1 * (1.f / 16.f);
    float var = s2 * (1.f / 16.f) - mu * mu;
    float rs = rsqrtf(var + 1e-5f);
    float4 gam = *(const float4*)&ln_g[lg * 4];
    float4 bet = *(const float4*)&ln_b[lg * 4];
    float n0_ = (g0 - mu) * rs * gam.x + bet.x;
    float n1_ = (g1 - mu) * rs * gam.y + bet.y;
    float n2_ = (g2 - mu) * rs * gam.z + bet.z;
    float n3_ = (g3 - mu) * rs * gam.w + bet.w;
    float mx = fmaxf(fmaxf(n0_, n1_), fmaxf(n2_, n3_));
    mx = fmaxf(mx, __shfl_xor(mx, 16)); mx = fmaxf(mx, __shfl_xor(mx, 32));
    float e0 = __expf(n0_ - mx), e1 = __expf(n1_ - mx), e2 = __expf(n2_ - mx), e3 = __expf(n3_ - mx);
    float es = e0 + e1 + e2 + e3;
    es += __shfl_xor(es, 16); es += __shfl_xor(es, 32);
    float inv = 1.f / es;
    float4 go; go.x = e0 * inv; go.y = e1 * inv; go.z = e2 * inv; go.w = e3 * inv;
    *(float4*)&gate[(size_t)(n0 + wid * 16 + lr) * NE + lg * 4] = go;
  }

  int wr = wid >> 2;    // h1-half (GEMM1 rows)
  int wc = wid & 3;     // token-quarter (GEMM1 cols)

  for (int e = 0; e < NE; ++e) {
    const unsigned short* W1e = W1f + (size_t)e * 65536;
    // --- GEMM1 (swapped): D[h1 64][tok 32] per wave, K=512, all from global ---
    f32x4 a1[4][2];
#pragma unroll
    for (int m = 0; m < 4; ++m)
#pragma unroll
      for (int n = 0; n < 2; ++n) a1[m][n] = (f32x4){0.f, 0.f, 0.f, 0.f};
    for (int ks = 0; ks < 16; ++ks) {
      int G = ks * 4 + lg;
      short8 av[4];
#pragma unroll
      for (int m = 0; m < 4; ++m)
        av[m] = *(const short8*)&W1e[(wr * 4 + m) * 8192 + G * 128 + lr * 8];
#pragma unroll
      for (int n = 0; n < 2; ++n) {
        short8 bv = *(const short8*)&xf[(size_t)((n0 >> 4) + wc * 2 + n) * 8192 + G * 128 + lr * 8];
#pragma unroll
        for (int m = 0; m < 4; ++m)
          a1[m][n] = __builtin_amdgcn_mfma_f32_16x16x32_bf16(av[m], bv, a1[m][n], 0, 0, 0);
      }
    }
    // --- BN1 + lrelu -> h1l[e&1], packed 8B swizzled writes ---
    unsigned short* hb = &h1l[e & 1][0];
#pragma unroll
    for (int m = 0; m < 4; ++m) {
      int c0 = wr * 64 + m * 16 + lg * 4;    // 4 consecutive h1 cols
      float4 mu4 = *(const float4*)&mean1[e * NH1 + c0];
      float4 is4 = *(const float4*)&istd1[e * NH1 + c0];
#pragma unroll
      for (int n = 0; n < 2; ++n) {
        int tok = wc * 32 + n * 16 + lr;
        ushort4_t pk;
        float v0 = (a1[m][n][0] - mu4.x) * is4.x; v0 = v0 >= 0.f ? v0 : 0.01f * v0;
        float v1 = (a1[m][n][1] - mu4.y) * is4.y; v1 = v1 >= 0.f ? v1 : 0.01f * v1;
        float v2 = (a1[m][n][2] - mu4.z) * is4.z; v2 = v2 >= 0.f ? v2 : 0.01f * v2;
        float v3 = (a1[m][n][3] - mu4.w) * is4.w; v3 = v3 >= 0.f ? v3 : 0.01f * v3;
        pk.x = f2bf(v0); pk.y = f2bf(v1); pk.z = f2bf(v2); pk.w = f2bf(v3);
        *(ushort4_t*)&hb[(tok * 128 + c0) ^ ((tok & 7) << 3)] = pk;
      }
    }
    __syncthreads();
    // --- GEMM2 (swapped): D[h2 64][tok 16] per wave, K=128 from h1l ---
    const unsigned short* W2e = W2f + e * 8192;
    int tok2 = wid * 16 + lr;
    f32x4 a2[4];
#pragma unroll
    for (int m2 = 0; m2 < 4; ++m2) a2[m2] = (f32x4){0.f, 0.f, 0.f, 0.f};
#pragma unroll
    for (int ks2 = 0; ks2 < 4; ++ks2) {
      short8 bv2 = *(const short8*)&hb[(tok2 * 128 + ks2 * 32 + lg * 8) ^ ((tok2 & 7) << 3)];
#pragma unroll
      for (int m2 = 0; m2 < 4; ++m2) {
        short8 av2 = *(const short8*)&W2e[m2 * 2048 + (ks2 * 4 + lg) * 128 + lr * 8];
        a2[m2] = __builtin_amdgcn_mfma_f32_16x16x32_bf16(av2, bv2, a2[m2], 0, 0, 0);
      }
    }
    // --- h2_pre direct packed global store (L2 merges into 128B lines) ---
    unsigned short* rowp = &h2p[(size_t)(n0 + tok2) * 1024 + e * 64];
#pragma unroll
    for (int m2 = 0; m2 < 4; ++m2) {
      ushort4_t pk;
      pk.x = f2bf(a2[m2][0]); pk.y = f2bf(a2[m2][1]);
      pk.z = f2bf(a2[m2][2]); pk.w = f2bf(a2[m2][3]);
      *(ushort4_t*)&rowp[m2 * 16 + lg * 4] = pk;
    }
  }
}

// ============ k_bn2stats: sum / sumsq over batch per (e, h2) ============
__global__ __launch_bounds__(1024) void k_bn2stats(const unsigned short* __restrict__ h2p,
                                                   float* __restrict__ s,
                                                   float* __restrict__ ss)
{
  int c = threadIdx.x;             // 0..1023 = (e*64+h)
  int n0 = blockIdx.x * 256;       // 256 blocks
  float a = 0.f, b = 0.f;
  for (int i = 0; i < 256; ++i) {
    float v = bf2f(h2p[(size_t)(n0 + i) * 1024 + c]);
    a += v; b += v * v;
  }
  atomicAdd(&s[c], a);
  atomicAdd(&ss[c], b);
}

// ============ k_tail: BN2+lrelu, score = h2n.v + bs, out = sum gate*score ======
__global__ __launch_bounds__(256) void k_tail(const unsigned short* __restrict__ h2p,
                                              const float* __restrict__ s,
                                              const float* __restrict__ ss,
                                              const float* __restrict__ vf,
                                              const float* __restrict__ gate,
                                              const float* __restrict__ bsp,
                                              float* __restrict__ out)
{
  int t = threadIdx.x;
  int l = t & 63, wid = t >> 6;
  int c0 = l * 16;
  float lm[16], li[16], lv[16];
#pragma unroll
  for (int j = 0; j < 16; ++j) {
    int c = c0 + j;
    float m = s[c] * (1.f / 65536.f);
    float var = ss[c] * (1.f / 65536.f) - m * m;
    lm[j] = m;
    li[j] = rsqrtf(var + 1e-4f);
    lv[j] = vf[c];
  }
  float bsv = bsp[0];
  for (int it = 0; it < 32; ++it) {
    int n = blockIdx.x * 128 + wid * 32 + it;
    const unsigned short* row = &h2p[(size_t)n * 1024 + c0];
    short8 v0 = *(const short8*)&row[0];
    short8 v1 = *(const short8*)&row[8];
    float p = 0.f;
#pragma unroll
    for (int j = 0; j < 8; ++j) {
      float h = bf2f((unsigned short)v0[j]);
      float hn = (h - lm[j]) * li[j];
      hn = hn >= 0.f ? hn : 0.01f * hn;
      p += hn * lv[j];
    }
#pragma unroll
    for (int j = 0; j < 8; ++j) {
      float h = bf2f((unsigned short)v1[j]);
      float hn = (h - lm[8 + j]) * li[8 + j];
      hn = hn >= 0.f ? hn : 0.01f * hn;
      p += hn * lv[8 + j];
    }
    p += __shfl_xor(p, 1);
    p += __shfl_xor(p, 2);
    float score = p + bsv;
    float gv = gate[(size_t)n * NE + (l >> 2)];
    float pr = gv * score;
    pr += __shfl_xor(pr, 4);
    pr += __shfl_xor(pr, 8);
    pr += __shfl_xor(pr, 16);
    pr += __shfl_xor(pr, 32);
    if (l == 0) out[n] = pr;
  }
}

extern "C" void kernel_launch(void* const* d_in, const int* in_sizes, int n_in,
                              void* d_out, int out_size, void* d_ws, size_t ws_size,
                              hipStream_t stream)
{
  (void)in_sizes; (void)n_in; (void)out_size; (void)ws_size;
  const float* x   = (const float*)d_in[0];
  const float* Wg  = (const float*)d_in[1];
  const float* bg  = (const float*)d_in[2];
  const float* lng = (const float*)d_in[3];
  const float* lnb = (const float*)d_in[4];
  const float* W1  = (const float*)d_in[5];
  const float* W2  = (const float*)d_in[6];
  const float* W3  = (const float*)d_in[7];
  const float* Ws  = (const float*)d_in[8];
  const float* bs  = (const float*)d_in[9];
  float* out = (float*)d_out;

  char* ws = (char*)d_ws;
  unsigned short* xf  = (unsigned short*)(ws + OFF_XF);
  unsigned short* h2p = (unsigned short*)(ws + OFF_H2);
  unsigned short* xTf = (unsigned short*)(ws + OFF_XTF);
  float* covp  = (float*)(ws + OFF_COVP);
  float* C     = (float*)(ws + OFF_C);
  float* gate  = (float*)(ws + OFF_GATE);
  unsigned short* W1f = (unsigned short*)(ws + OFF_W1F);
  unsigned short* W1t = (unsigned short*)(ws + OFF_W1T);
  unsigned short* W2f = (unsigned short*)(ws + OFF_W2F);
  unsigned short* Wgf = (unsigned short*)(ws + OFF_WGF);
  float* vf    = (float*)(ws + OFF_V);
  float* xbar  = (float*)(ws + OFF_XBAR);
  float* bn2s  = (float*)(ws + OFF_BN2S);
  float* bn2ss = (float*)(ws + OFF_BN2SS);
  float* mean1 = (float*)(ws + OFF_MEAN1);
  float* istd1 = (float*)(ws + OFF_ISTD1);

  hipLaunchKernelGGL(k_wprep, dim3(1106), dim3(256), 0, stream,
                     W1, W2, W3, Wg, Ws, W1f, W1t, W2f, Wgf, vf, xbar);
  hipLaunchKernelGGL(k_prep, dim3(8192), dim3(256), 0, stream, x, xf, xTf, xbar);
  hipLaunchKernelGGL(k_cov, dim3(1280), dim3(256), 0, stream, xTf, covp);
  hipLaunchKernelGGL(k_covred, dim3(640), dim3(256), 0, stream, covp, C);
  hipLaunchKernelGGL(k_bn1, dim3(256), dim3(256), 0, stream, C, xbar, W1t, mean1, istd1);
  hipLaunchKernelGGL(k_main, dim3(512), dim3(512), 0, stream,
                     xf, Wgf, W1f, W2f, bg, lng, lnb, mean1, istd1, gate, h2p);
  hipLaunchKernelGGL(k_bn2stats, dim3(256), dim3(1024), 0, stream, h2p, bn2s, bn2ss);
  hipLaunchKernelGGL(k_tail, dim3(512), dim3(256), 0, stream, h2p, bn2s, bn2ss, vf, gate, bs, out);
}

// Round 5
// 748.881 us; speedup vs baseline: 1.5475x; 1.5475x over previous
//
// MOE anomaly detection — MI355X round 5.
// r4 post-mortem: FETCH 954MB = x re-read 16x from HBM (L2 thrash), and
// W1-from-L2-per-wave caps MfmaUtil at ~11-20% (L2 = 56 B/cy/CU).
// Fix: canonical LDS-staged GEMM in k_main: x-chunk + W1-chunk double-buffered
// via global_load_lds(16B) from frag-ordered arrays; both MFMA operands read
// from LDS (256 B/cy). h1l aliases the consumed stage half -> 128KB LDS total.
// GEMM2 + epilogues reuse r4's verified code. Other kernels unchanged.
#include <hip/hip_runtime.h>
#include <stdint.h>

#define NTOK 65536
#define DDIM 512
#define NE   16
#define NH1  128
#define NH2  64
#define NR   32

typedef __attribute__((ext_vector_type(8))) short short8;
typedef __attribute__((ext_vector_type(4))) unsigned short ushort4_t;
typedef __attribute__((ext_vector_type(4))) float f32x4;

__device__ __forceinline__ unsigned short f2bf(float f) {
  union { float f; uint32_t u; } v; v.f = f;
  uint32_t u = v.u;
  return (unsigned short)((u + 0x7FFFu + ((u >> 16) & 1u)) >> 16);
}
__device__ __forceinline__ float bf2f(unsigned short h) {
  union { uint32_t u; float f; } v; v.u = ((uint32_t)h) << 16;
  return v.f;
}

// ---------------- ws layout (bytes) ----------------
#define OFF_XF     ((size_t)0)            // bf16 xf   frag-tiled             67108864
#define OFF_H2     ((size_t)67108864)     // bf16 h2_pre [N][16][64]         134217728
#define OFF_XTF    ((size_t)67108864)     // bf16 xTf  frag-tiled (ALIAS h2)  67108864
#define OFF_COVP   ((size_t)134217728)    // f32 covp [1280][128][128] (ALIAS)83886080
#define OFF_C      ((size_t)218103808)    // f32 C [512][512]                  1048576
#define OFF_GATE   ((size_t)219152384)    // f32 gate [N][16]                  4194304
#define OFF_W1F    ((size_t)223346688)    // bf16 W1f frag-tiled               2097152
#define OFF_W1T    ((size_t)225443840)    // bf16 W1t row-major (k_bn1)        2097152
#define OFF_W2F    ((size_t)227540992)    // bf16 W2f frag-tiled [16][8192]sh   262144
#define OFF_WGF    ((size_t)227803136)    // bf16 Wgf frag-tiled                 16384
#define OFF_V      ((size_t)227819520)    // f32 v=W3@Ws [16][64]                 4096
#define OFF_XBAR   ((size_t)227823616)    // f32 xbar[512]   (zero region)        2048
#define OFF_BN2S   ((size_t)227825664)    // f32 bn2 sum[1024]                    4096
#define OFF_BN2SS  ((size_t)227829760)    // f32 bn2 sumsq[1024]                  4096
#define OFF_MEAN1  ((size_t)227833856)    // f32 mean1[16][128]                   8192
#define OFF_ISTD1  ((size_t)227842048)    // f32 istd1[16][128]                   8192

// ============ k_wprep: weight convert to frag layouts + fold + zero ============
__global__ __launch_bounds__(256) void k_wprep(
    const float* __restrict__ W1, const float* __restrict__ W2,
    const float* __restrict__ W3, const float* __restrict__ Wg,
    const float* __restrict__ Ws,
    unsigned short* __restrict__ W1f, unsigned short* __restrict__ W1t,
    unsigned short* __restrict__ W2f, unsigned short* __restrict__ Wgf,
    float* __restrict__ vfold, float* __restrict__ zeroreg)
{
  int b = blockIdx.x, t = threadIdx.x;
  if (b < 512) {            // W1 [E][D][H1] -> W1f frag: e,h-tile,G=d>>3,h&15,d&7
    int f = b * 256 + t;
    int d8 = f & 63, h = (f >> 6) & 127, e = f >> 13;
    short8 s;
#pragma unroll
    for (int i = 0; i < 8; ++i)
      s[i] = (short)f2bf(W1[((e * DDIM + d8 * 8 + i) * NH1) + h]);
    *(short8*)&W1f[e * 65536 + (h >> 4) * 8192 + d8 * 128 + (h & 15) * 8] = s;
  } else if (b < 1024) {    // W1 -> W1t [E][H1][D] row-major (for k_bn1)
    int f = (b - 512) * 256 + t;
    int h = f & 127, d8 = (f >> 7) & 63, e = f >> 13;
    short8 s;
#pragma unroll
    for (int i = 0; i < 8; ++i)
      s[i] = (short)f2bf(W1[((e * DDIM + d8 * 8 + i) * NH1) + h]);
    *(short8*)&W1t[(e * NH1 + h) * DDIM + d8 * 8] = s;
  } else if (b < 1088) {    // W2 [E][H1][H2] -> W2f frag
    int f = (b - 1024) * 256 + t;
    int h18 = f & 15, h2 = (f >> 4) & 63, e = f >> 10;
    short8 s;
#pragma unroll
    for (int i = 0; i < 8; ++i)
      s[i] = (short)f2bf(W2[((e * NH1 + h18 * 8 + i) * NH2) + h2]);
    *(short8*)&W2f[e * 8192 + (h2 >> 4) * 2048 + h18 * 128 + (h2 & 15) * 8] = s;
  } else if (b < 1092) {    // Wg [D][E] -> Wgf frag (single 16-col tile)
    int f = (b - 1088) * 256 + t;
    int e = f & 15, dg = f >> 4;
    short8 s;
#pragma unroll
    for (int i = 0; i < 8; ++i)
      s[i] = (short)f2bf(Wg[(dg * 8 + i) * NE + e]);
    *(short8*)&Wgf[dg * 128 + e * 8] = s;
  } else if (b < 1096) {    // vfold[e][h] = sum_r W3[e][h][r]*Ws[r]
    int f = (b - 1092) * 256 + t;
    if (f < NE * NH2) {
      int h = f & 63, e = f >> 6;
      float a = 0.f;
#pragma unroll
      for (int r = 0; r < NR; ++r) a += W3[(e * NH2 + h) * NR + r] * Ws[r];
      vfold[e * NH2 + h] = a;
    }
  } else {                  // zero xbar(512)+bn2s(1024)+bn2ss(1024)
    int f = (b - 1096) * 256 + t;
    if (f < 2560) zeroreg[f] = 0.f;
  }
}

// ============ k_prep: x fp32 -> xf (token-frag) + xTf (d-frag) + column sums ====
__global__ __launch_bounds__(256) void k_prep(const float* __restrict__ x,
                                              unsigned short* __restrict__ xf,
                                              unsigned short* __restrict__ xTf,
                                              float* __restrict__ xbar)
{
  __shared__ unsigned short tl[64 * 72];
  __shared__ float red[16 * 64];
  int b = blockIdx.x, t = threadIdx.x;
  int dt = b >> 10, nt = b & 1023;
  int d0 = dt * 64, n0 = nt * 64;
  int rg = t >> 4, c4 = (t & 15) * 4;
  float s0 = 0, s1 = 0, s2 = 0, s3 = 0;
#pragma unroll
  for (int i = 0; i < 4; ++i) {
    int r = i * 16 + rg;
    float4 v = *(const float4*)&x[(size_t)(n0 + r) * DDIM + d0 + c4];
    s0 += v.x; s1 += v.y; s2 += v.z; s3 += v.w;
    ushort4_t u;
    u.x = f2bf(v.x); u.y = f2bf(v.y); u.z = f2bf(v.z); u.w = f2bf(v.w);
    tl[(c4 + 0) * 72 + r] = u.x;
    tl[(c4 + 1) * 72 + r] = u.y;
    tl[(c4 + 2) * 72 + r] = u.z;
    tl[(c4 + 3) * 72 + r] = u.w;
    int n = n0 + r, dd = d0 + c4;
    *(ushort4_t*)&xf[(size_t)(n >> 4) * 8192 + (dd >> 3) * 128 + (n & 15) * 8 + (dd & 7)] = u;
  }
  red[rg * 64 + c4 + 0] = s0;
  red[rg * 64 + c4 + 1] = s1;
  red[rg * 64 + c4 + 2] = s2;
  red[rg * 64 + c4 + 3] = s3;
  __syncthreads();
  if (t < 64) {
    float s = 0;
#pragma unroll
    for (int k = 0; k < 16; ++k) s += red[k * 64 + t];
    atomicAdd(&xbar[d0 + t], s);
  }
#pragma unroll
  for (int ii = 0; ii < 2; ++ii) {
    int cid = ii * 256 + t;
    int dl = cid >> 3, ng = cid & 7;
    short8 v = *(short8*)&tl[dl * 72 + ng * 8];
    int dg = d0 + dl;
    *(short8*)&xTf[(size_t)(dg >> 4) * 1048576 + (size_t)((n0 >> 3) + ng) * 128 + (dg & 15) * 8] = v;
  }
}

// ============ k_cov: covp partials of C = x^T x (unchanged) ============
__global__ __launch_bounds__(256, 4) void k_cov(const unsigned short* __restrict__ xTf,
                                                float* __restrict__ covp)
{
  int bid = blockIdx.x, t = threadIdx.x;
  int chunk = bid / 10, tile = bid - chunk * 10;
  int ti = tile < 4 ? 0 : tile < 7 ? 1 : tile < 9 ? 2 : 3;
  int tj = tile < 4 ? tile : tile < 7 ? tile - 3 : tile < 9 ? tile - 5 : 3;
  int l = t & 63, wid = t >> 6;
  int lr = l & 15, lg = l >> 4;
  int rt = ti * 8 + (wid >> 1) * 4;
  int ct = tj * 8 + (wid & 1) * 4;
  int G0 = chunk * 64;
  f32x4 acc[4][4];
#pragma unroll
  for (int m = 0; m < 4; ++m)
#pragma unroll
    for (int n = 0; n < 4; ++n) acc[m][n] = (f32x4){0.f, 0.f, 0.f, 0.f};
  for (int ksi = 0; ksi < 16; ++ksi) {
    size_t G = (size_t)(G0 + ksi * 4 + lg);
    short8 av[4], bv[4];
#pragma unroll
    for (int m = 0; m < 4; ++m)
      av[m] = *(const short8*)&xTf[(size_t)(rt + m) * 1048576 + G * 128 + lr * 8];
#pragma unroll
    for (int n = 0; n < 4; ++n)
      bv[n] = *(const short8*)&xTf[(size_t)(ct + n) * 1048576 + G * 128 + lr * 8];
#pragma unroll
    for (int m = 0; m < 4; ++m)
#pragma unroll
      for (int n = 0; n < 4; ++n)
        acc[m][n] = __builtin_amdgcn_mfma_f32_16x16x32_bf16(av[m], bv[n], acc[m][n], 0, 0, 0);
  }
  float* outp = &covp[(size_t)bid * 16384];
#pragma unroll
  for (int m = 0; m < 4; ++m)
#pragma unroll
    for (int n = 0; n < 4; ++n)
#pragma unroll
      for (int r = 0; r < 4; ++r) {
        int rl = (wid >> 1) * 64 + m * 16 + lg * 4 + r;
        int cl = (wid & 1) * 64 + n * 16 + lr;
        outp[rl * 128 + cl] = acc[m][n][r];
      }
}

__global__ __launch_bounds__(256) void k_covred(const float* __restrict__ covp,
                                                float* __restrict__ C)
{
  int bid = blockIdx.x, t = threadIdx.x;
  int tile = bid >> 6;
  int el = (bid & 63) * 256 + t;
  int r = el >> 7, c = el & 127;
  int ti = tile < 4 ? 0 : tile < 7 ? 1 : tile < 9 ? 2 : 3;
  int tj = tile < 4 ? tile : tile < 7 ? tile - 3 : tile < 9 ? tile - 5 : 3;
  float s = 0.f;
#pragma unroll 4
  for (int ch = 0; ch < 128; ++ch)
    s += covp[(size_t)(ch * 10 + tile) * 16384 + r * 128 + c];
  int gi = ti * 128 + r, gj = tj * 128 + c;
  C[gi * 512 + gj] = s;
  if (ti != tj) C[gj * 512 + gi] = s;
}

// ============ k_bn1 (unchanged) ============
__global__ __launch_bounds__(256) void k_bn1(const float* __restrict__ C,
                                             const float* __restrict__ xbar,
                                             const unsigned short* __restrict__ W1t,
                                             float* __restrict__ mean1,
                                             float* __restrict__ istd1)
{
  __shared__ float wl[8][512];
  __shared__ float rq[256][8];
  __shared__ float rm[256][8];
  int b = blockIdx.x, t = threadIdx.x;
  int e = b >> 4, ho = (b & 15) * 8;
  for (int f = t; f < 8 * 512; f += 256) {
    int c = f >> 9, d = f & 511;
    wl[c][d] = bf2f(W1t[(e * NH1 + ho + c) * DDIM + d]);
  }
  __syncthreads();
  float q[8] = {0, 0, 0, 0, 0, 0, 0, 0};
  float m[8] = {0, 0, 0, 0, 0, 0, 0, 0};
#pragma unroll
  for (int half = 0; half < 2; ++half) {
    int i = half * 256 + t;
    float rd[8] = {0, 0, 0, 0, 0, 0, 0, 0};
    const float* crow = &C[i * 512];
    for (int j = 0; j < 512; j += 4) {
      float4 cv = *(const float4*)&crow[j];
#pragma unroll
      for (int c = 0; c < 8; ++c)
        rd[c] += cv.x * wl[c][j] + cv.y * wl[c][j + 1] + cv.z * wl[c][j + 2] + cv.w * wl[c][j + 3];
    }
    float xb = xbar[i];
#pragma unroll
    for (int c = 0; c < 8; ++c) { q[c] += wl[c][i] * rd[c]; m[c] += wl[c][i] * xb; }
  }
#pragma unroll
  for (int c = 0; c < 8; ++c) { rq[t][c] = q[c]; rm[t][c] = m[c]; }
  __syncthreads();
  for (int s = 128; s > 0; s >>= 1) {
    if (t < s)
#pragma unroll
      for (int c = 0; c < 8; ++c) { rq[t][c] += rq[t + s][c]; rm[t][c] += rm[t + s][c]; }
    __syncthreads();
  }
  if (t < 8) {
    float mean = rm[0][t] * (1.f / 65536.f);
    float var = rq[0][t] * (1.f / 65536.f) - mean * mean;
    mean1[e * NH1 + ho + t] = mean;
    istd1[e * NH1 + ho + t] = rsqrtf(var + 1e-4f);
  }
}

// ============ k_main v3: LDS-staged dbuf GEMM1 + aliased h1l + GEMM2 ============
// 512 thr / 8 waves / 128 tok / 512 blocks. LDS = 2x64KB stage dbuf (x 32KB +
// W1 32KB per half); h1l aliases the consumed half. Both MFMA operands from LDS.
__global__ __launch_bounds__(512, 2) void k_main(
    const unsigned short* __restrict__ xf, const unsigned short* __restrict__ Wgf,
    const unsigned short* __restrict__ W1f, const unsigned short* __restrict__ W2f,
    const float* __restrict__ bg, const float* __restrict__ ln_g,
    const float* __restrict__ ln_b, const float* __restrict__ mean1,
    const float* __restrict__ istd1, float* __restrict__ gate,
    unsigned short* __restrict__ h2p)
{
  __shared__ unsigned short stg[2][32768];  // 2 x 64KB: [x: 0..16383 | W1: 16384..32767]
  int t = threadIdx.x;
  int n0 = blockIdx.x * 128;
  int l = t & 63, wid = t >> 6;
  int lr = l & 15, lg = l >> 4;

  {  // ---- gating (r4-verified): D[e][tok] = mfma(Wgf, xf); LN+softmax ----
    size_t tokT = (size_t)((n0 >> 4) + wid);
    f32x4 ga = (f32x4){0.f, 0.f, 0.f, 0.f};
    for (int ks = 0; ks < 16; ++ks) {
      int G = ks * 4 + lg;
      short8 avg = *(const short8*)&Wgf[G * 128 + lr * 8];
      short8 bvx = *(const short8*)&xf[tokT * 8192 + G * 128 + lr * 8];
      ga = __builtin_amdgcn_mfma_f32_16x16x32_bf16(avg, bvx, ga, 0, 0, 0);
    }
    float4 bg4 = *(const float4*)&bg[lg * 4];
    float g0 = ga[0] + bg4.x, g1 = ga[1] + bg4.y, g2 = ga[2] + bg4.z, g3 = ga[3] + bg4.w;
    float s1 = g0 + g1 + g2 + g3;
    float s2 = g0 * g0 + g1 * g1 + g2 * g2 + g3 * g3;
    s1 += __shfl_xor(s1, 16); s1 += __shfl_xor(s1, 32);
    s2 += __shfl_xor(s2, 16); s2 += __shfl_xor(s2, 32);
    float mu = s1 * (1.f / 16.f);
    float var = s2 * (1.f / 16.f) - mu * mu;
    float rs = rsqrtf(var + 1e-5f);
    float4 gam = *(const float4*)&ln_g[lg * 4];
    float4 bet = *(const float4*)&ln_b[lg * 4];
    float n0_ = (g0 - mu) * rs * gam.x + bet.x;
    float n1_ = (g1 - mu) * rs * gam.y + bet.y;
    float n2_ = (g2 - mu) * rs * gam.z + bet.z;
    float n3_ = (g3 - mu) * rs * gam.w + bet.w;
    float mx = fmaxf(fmaxf(n0_, n1_), fmaxf(n2_, n3_));
    mx = fmaxf(mx, __shfl_xor(mx, 16)); mx = fmaxf(mx, __shfl_xor(mx, 32));
    float e0 = __expf(n0_ - mx), e1 = __expf(n1_ - mx), e2 = __expf(n2_ - mx), e3 = __expf(n3_ - mx);
    float es = e0 + e1 + e2 + e3;
    es += __shfl_xor(es, 16); es += __shfl_xor(es, 32);
    float inv = 1.f / es;
    float4 go; go.x = e0 * inv; go.y = e1 * inv; go.z = e2 * inv; go.w = e3 * inv;
    *(float4*)&gate[(size_t)(n0 + wid * 16 + lr) * NE + lg * 4] = go;
  }

  // stage chunk (e,kc) into stg[b]: wave `wid` stages x tok-tile wid and W1
  // h1-tile wid; 4 KB each via 4x global_load_lds(16B). LDS dest wave-uniform,
  // +lane*16 implicit == frag-linear layout.
  auto STAGE = [&](int b, int e, int kc) {
    const unsigned short* xsrc = xf + ((size_t)(n0 >> 4) + wid) * 8192 + kc * 2048 + l * 8;
    const unsigned short* wsrc = W1f + (size_t)e * 65536 + (size_t)wid * 8192 + kc * 2048 + l * 8;
    unsigned short* xdst = &stg[b][wid * 2048];
    unsigned short* wdst = &stg[b][16384 + wid * 2048];
#pragma unroll
    for (int c = 0; c < 4; ++c) {
      __builtin_amdgcn_global_load_lds(
          (const __attribute__((address_space(1))) void*)(xsrc + c * 512),
          (__attribute__((address_space(3))) void*)(xdst + c * 512), 16, 0, 0);
      __builtin_amdgcn_global_load_lds(
          (const __attribute__((address_space(1))) void*)(wsrc + c * 512),
          (__attribute__((address_space(3))) void*)(wdst + c * 512), 16, 0, 0);
    }
  };

  int wr = wid >> 2;    // h1-half (0..1)
  int wc = wid & 3;     // token-quarter (0..3)
  int hq = wid >> 1;    // GEMM2 h2-tile (0..3)
  int th = wid & 1;     // GEMM2 token-half (0..1)

  STAGE(0, 0, 0);
  __syncthreads();      // implicit vmcnt(0): buf0 ready
  int cur = 0;

  for (int e = 0; e < NE; ++e) {
    f32x4 a1[4][2];
#pragma unroll
    for (int m = 0; m < 4; ++m)
#pragma unroll
      for (int n = 0; n < 2; ++n) a1[m][n] = (f32x4){0.f, 0.f, 0.f, 0.f};

    for (int kc = 0; kc < 4; ++kc) {
      int step = e * 4 + kc;
      if (step < 63) STAGE(cur ^ 1, (step + 1) >> 2, (step + 1) & 3);
      // compute chunk from stg[cur]: 4 K32-steps, 8 MFMA each
#pragma unroll
      for (int s = 0; s < 4; ++s) {
        short8 av[4], bv[2];
#pragma unroll
        for (int m = 0; m < 4; ++m)
          av[m] = *(short8*)&stg[cur][16384 + (wr * 4 + m) * 2048 + s * 512 + l * 8];
#pragma unroll
        for (int n = 0; n < 2; ++n)
          bv[n] = *(short8*)&stg[cur][(wc * 2 + n) * 2048 + s * 512 + l * 8];
#pragma unroll
        for (int n = 0; n < 2; ++n)
#pragma unroll
          for (int m = 0; m < 4; ++m)
            a1[m][n] = __builtin_amdgcn_mfma_f32_16x16x32_bf16(av[m], bv[n], a1[m][n], 0, 0, 0);
      }
      __syncthreads();  // drains vmcnt (next buf ready) + retires cur reads
      cur ^= 1;
    }

    // --- BN1 + lrelu -> h1l (aliased into consumed half stg[cur^1]) ---
    unsigned short* hb = &stg[cur ^ 1][0];
#pragma unroll
    for (int m = 0; m < 4; ++m) {
      int c0 = wr * 64 + m * 16 + lg * 4;
      float4 mu4 = *(const float4*)&mean1[e * NH1 + c0];
      float4 is4 = *(const float4*)&istd1[e * NH1 + c0];
#pragma unroll
      for (int n = 0; n < 2; ++n) {
        int tok = wc * 32 + n * 16 + lr;
        ushort4_t pk;
        float v0 = (a1[m][n][0] - mu4.x) * is4.x; v0 = v0 >= 0.f ? v0 : 0.01f * v0;
        float v1 = (a1[m][n][1] - mu4.y) * is4.y; v1 = v1 >= 0.f ? v1 : 0.01f * v1;
        float v2 = (a1[m][n][2] - mu4.z) * is4.z; v2 = v2 >= 0.f ? v2 : 0.01f * v2;
        float v3 = (a1[m][n][3] - mu4.w) * is4.w; v3 = v3 >= 0.f ? v3 : 0.01f * v3;
        pk.x = f2bf(v0); pk.y = f2bf(v1); pk.z = f2bf(v2); pk.w = f2bf(v3);
        *(ushort4_t*)&hb[(tok * 128 + c0) ^ ((tok & 7) << 3)] = pk;
      }
    }
    __syncthreads();

    // --- GEMM2: wave = [16 h2 x 64 tok]; A=W2f (L2, shared by wave pairs) ---
    const unsigned short* W2e = W2f + e * 8192;
    f32x4 a2[4];
#pragma unroll
    for (int n = 0; n < 4; ++n) a2[n] = (f32x4){0.f, 0.f, 0.f, 0.f};
#pragma unroll
    for (int ks2 = 0; ks2 < 4; ++ks2) {
      short8 av2 = *(const short8*)&W2e[hq * 2048 + (ks2 * 4 + lg) * 128 + lr * 8];
#pragma unroll
      for (int n = 0; n < 4; ++n) {
        int tok = th * 64 + n * 16 + lr;
        short8 bv2 = *(short8*)&hb[(tok * 128 + ks2 * 32 + lg * 8) ^ ((tok & 7) << 3)];
        a2[n] = __builtin_amdgcn_mfma_f32_16x16x32_bf16(av2, bv2, a2[n], 0, 0, 0);
      }
    }
#pragma unroll
    for (int n = 0; n < 4; ++n) {
      int tok = th * 64 + n * 16 + lr;
      ushort4_t pk;
      pk.x = f2bf(a2[n][0]); pk.y = f2bf(a2[n][1]);
      pk.z = f2bf(a2[n][2]); pk.w = f2bf(a2[n][3]);
      *(ushort4_t*)&h2p[(size_t)(n0 + tok) * 1024 + e * 64 + hq * 16 + lg * 4] = pk;
    }
    __syncthreads();  // protect hb (h1l) from next expert's stage into this half
  }
}

// ============ k_bn2stats (unchanged) ============
__global__ __launch_bounds__(1024) void k_bn2stats(const unsigned short* __restrict__ h2p,
                                                   float* __restrict__ s,
                                                   float* __restrict__ ss)
{
  int c = threadIdx.x;
  int n0 = blockIdx.x * 256;
  float a = 0.f, b = 0.f;
  for (int i = 0; i < 256; ++i) {
    float v = bf2f(h2p[(size_t)(n0 + i) * 1024 + c]);
    a += v; b += v * v;
  }
  atomicAdd(&s[c], a);
  atomicAdd(&ss[c], b);
}

// ============ k_tail (unchanged) ============
__global__ __launch_bounds__(256) void k_tail(const unsigned short* __restrict__ h2p,
                                              const float* __restrict__ s,
                                              const float* __restrict__ ss,
                                              const float* __restrict__ vf,
                                              const float* __restrict__ gate,
                                              const float* __restrict__ bsp,
                                              float* __restrict__ out)
{
  int t = threadIdx.x;
  int l = t & 63, wid = t >> 6;
  int c0 = l * 16;
  float lm[16], li[16], lv[16];
#pragma unroll
  for (int j = 0; j < 16; ++j) {
    int c = c0 + j;
    float m = s[c] * (1.f / 65536.f);
    float var = ss[c] * (1.f / 65536.f) - m * m;
    lm[j] = m;
    li[j] = rsqrtf(var + 1e-4f);
    lv[j] = vf[c];
  }
  float bsv = bsp[0];
  for (int it = 0; it < 32; ++it) {
    int n = blockIdx.x * 128 + wid * 32 + it;
    const unsigned short* row = &h2p[(size_t)n * 1024 + c0];
    short8 v0 = *(const short8*)&row[0];
    short8 v1 = *(const short8*)&row[8];
    float p = 0.f;
#pragma unroll
    for (int j = 0; j < 8; ++j) {
      float h = bf2f((unsigned short)v0[j]);
      float hn = (h - lm[j]) * li[j];
      hn = hn >= 0.f ? hn : 0.01f * hn;
      p += hn * lv[j];
    }
#pragma unroll
    for (int j = 0; j < 8; ++j) {
      float h = bf2f((unsigned short)v1[j]);
      float hn = (h - lm[8 + j]) * li[8 + j];
      hn = hn >= 0.f ? hn : 0.01f * hn;
      p += hn * lv[8 + j];
    }
    p += __shfl_xor(p, 1);
    p += __shfl_xor(p, 2);
    float score = p + bsv;
    float gv = gate[(size_t)n * NE + (l >> 2)];
    float pr = gv * score;
    pr += __shfl_xor(pr, 4);
    pr += __shfl_xor(pr, 8);
    pr += __shfl_xor(pr, 16);
    pr += __shfl_xor(pr, 32);
    if (l == 0) out[n] = pr;
  }
}

extern "C" void kernel_launch(void* const* d_in, const int* in_sizes, int n_in,
                              void* d_out, int out_size, void* d_ws, size_t ws_size,
                              hipStream_t stream)
{
  (void)in_sizes; (void)n_in; (void)out_size; (void)ws_size;
  const float* x   = (const float*)d_in[0];
  const float* Wg  = (const float*)d_in[1];
  const float* bg  = (const float*)d_in[2];
  const float* lng = (const float*)d_in[3];
  const float* lnb = (const float*)d_in[4];
  const float* W1  = (const float*)d_in[5];
  const float* W2  = (const float*)d_in[6];
  const float* W3  = (const float*)d_in[7];
  const float* Ws  = (const float*)d_in[8];
  const float* bs  = (const float*)d_in[9];
  float* out = (float*)d_out;

  char* ws = (char*)d_ws;
  unsigned short* xf  = (unsigned short*)(ws + OFF_XF);
  unsigned short* h2p = (unsigned short*)(ws + OFF_H2);
  unsigned short* xTf = (unsigned short*)(ws + OFF_XTF);
  float* covp  = (float*)(ws + OFF_COVP);
  float* C     = (float*)(ws + OFF_C);
  float* gate  = (float*)(ws + OFF_GATE);
  unsigned short* W1f = (unsigned short*)(ws + OFF_W1F);
  unsigned short* W1t = (unsigned short*)(ws + OFF_W1T);
  unsigned short* W2f = (unsigned short*)(ws + OFF_W2F);
  unsigned short* Wgf = (unsigned short*)(ws + OFF_WGF);
  float* vf    = (float*)(ws + OFF_V);
  float* xbar  = (float*)(ws + OFF_XBAR);
  float* bn2s  = (float*)(ws + OFF_BN2S);
  float* bn2ss = (float*)(ws + OFF_BN2SS);
  float* mean1 = (float*)(ws + OFF_MEAN1);
  float* istd1 = (float*)(ws + OFF_ISTD1);

  hipLaunchKernelGGL(k_wprep, dim3(1106), dim3(256), 0, stream,
                     W1, W2, W3, Wg, Ws, W1f, W1t, W2f, Wgf, vf, xbar);
  hipLaunchKernelGGL(k_prep, dim3(8192), dim3(256), 0, stream, x, xf, xTf, xbar);
  hipLaunchKernelGGL(k_cov, dim3(1280), dim3(256), 0, stream, xTf, covp);
  hipLaunchKernelGGL(k_covred, dim3(640), dim3(256), 0, stream, covp, C);
  hipLaunchKernelGGL(k_bn1, dim3(256), dim3(256), 0, stream, C, xbar, W1t, mean1, istd1);
  hipLaunchKernelGGL(k_main, dim3(512), dim3(512), 0, stream,
                     xf, Wgf, W1f, W2f, bg, lng, lnb, mean1, istd1, gate, h2p);
  hipLaunchKernelGGL(k_bn2stats, dim3(256), dim3(1024), 0, stream, h2p, bn2s, bn2ss);
  hipLaunchKernelGGL(k_tail, dim3(512), dim3(256), 0, stream, h2p, bn2s, bn2ss, vf, gate, bs, out);
}